// Round 11
// baseline (796.665 us; speedup 1.0000x reference)
//
#include <hip/hip_runtime.h>
#include <hip/hip_bf16.h>

#define BB   1024
#define NNUM 16
#define NCAT 16
#define HH   64
#define VV   100
#define KK   8
#define CC   32
#define CH   2048      // C*H
#define FULLW 2560     // (K+C)*H

// workspace offsets (in floats)
#define OFF_FE3   0u
#define OFF_X1    2097152u
#define OFF_X2    4194304u
#define OFF_G     6291456u   // feat @ gcn1_w  (B x H)
#define OFF_SIMP  6356992u   // raw s (B*C)
#define OFF_P     6389760u   // p dense (B*C)
#define OFF_ROWE  6422528u   // rowE, position-indexed [c][ii]
#define OFF_DINV  6455296u   // dpos = dinv, position-indexed [c][ii]
#define OFF_F     6488064u   // fpos = dinv/sqrt(Z'), position-indexed [c][ii]
#define OFF_STATS 6520832u   // [0,1]=num sum/ssq [2,3]=cat [4,5]=imp
#define OFF_Z     6520840u   // per-channel Z (C)
#define OFF_X1S   6520872u   // per-channel sum/ssq of relu(x1) (2C)
#define OFF_X2S   6520936u   // per-channel sum/ssq of relu(x2) (2C)
#define OFF_COLS  6521000u   // int: sorted top-k indices (B*K)
#define OFF_LIST  6529192u   // int: per-channel row lists (C*B)
#define OFF_CNT   6561960u   // int: per-channel counts (C)
#define OFF_AOFF  6561992u   // int: prefix offsets of n_c^2 (C+1)
#define OFF_AN    6562048u   // compact E matrices, worst 8388608 floats

__device__ inline float wsum64(float v){
  #pragma unroll
  for (int o = 32; o; o >>= 1) v += __shfl_xor(v, o);
  return v;
}

// ---- K0: zero the atomic accumulators --------------------------------------
__global__ __launch_bounds__(256) void k_init(float* ws){
  int t = threadIdx.x;
  if (t < 8)  ws[OFF_STATS + t] = 0.f;
  if (t < 64) ws[OFF_X1S + t] = 0.f;
  if (t < 64) ws[OFF_X2S + t] = 0.f;
  if (t < 32) ws[OFF_Z + t] = 0.f;
}

// ---- K1: fused fe_num + fe_cat RAW (float4/thread), stats accumulated ------
__global__ __launch_bounds__(256) void k_fe(const float* __restrict__ nd,
                                            const float* __restrict__ nw,
                                            const float* __restrict__ nb,
                                            const int* __restrict__ cd,
                                            const float* __restrict__ emb,
                                            float* __restrict__ ws){
  float* fe3 = ws + OFF_FE3;
  float lsn = 0.f, lssn = 0.f, lsc = 0.f, lssc = 0.f;
  int idx = blockIdx.x*256 + threadIdx.x;          // < 524288 (2048 blocks)
  {
    int h4 = idx & 15, fn = (idx >> 4) & 15, b = (idx >> 8) & 1023;
    bool isNum = (idx < 262144);
    if (isNum){
      float s = nd[b*NNUM + fn];
      float4 w = *(const float4*)&nw[fn*HH + h4*4];
      float4 bi = *(const float4*)&nb[fn*HH + h4*4];
      float4 v;
      v.x = fmaxf(s*w.x + bi.x, 0.f);
      v.y = fmaxf(s*w.y + bi.y, 0.f);
      v.z = fmaxf(s*w.z + bi.z, 0.f);
      v.w = fmaxf(s*w.w + bi.w, 0.f);
      *(float4*)&fe3[b*CH + fn*HH + h4*4] = v;
      lsn = v.x+v.y+v.z+v.w;
      lssn = v.x*v.x+v.y*v.y+v.z*v.z+v.w*v.w;
    } else {
      int j = cd[b*NCAT + fn];
      float4 v = *(const float4*)&emb[((size_t)fn*VV + j)*HH + h4*4];
      *(float4*)&fe3[b*CH + (NNUM + fn)*HH + h4*4] = v;
      lsc = v.x+v.y+v.z+v.w;
      lssc = v.x*v.x+v.y*v.y+v.z*v.z+v.w*v.w;
    }
  }
  __shared__ float sh[16];
  lsn = wsum64(lsn); lssn = wsum64(lssn);
  lsc = wsum64(lsc); lssc = wsum64(lssc);
  int w = threadIdx.x >> 6;
  if ((threadIdx.x & 63) == 0){ sh[w] = lsn; sh[4+w] = lssn; sh[8+w] = lsc; sh[12+w] = lssc; }
  __syncthreads();
  if (threadIdx.x == 0){
    if (blockIdx.x < 1024){
      atomicAdd(ws + OFF_STATS + 0, sh[0]+sh[1]+sh[2]+sh[3]);
      atomicAdd(ws + OFF_STATS + 1, sh[4]+sh[5]+sh[6]+sh[7]);
    } else {
      atomicAdd(ws + OFF_STATS + 2, sh[8]+sh[9]+sh[10]+sh[11]);
      atomicAdd(ws + OFF_STATS + 3, sh[12]+sh[13]+sh[14]+sh[15]);
    }
  }
}

// ---- K4: feature-importance head (normalizes raw fe3 on the fly) -----------
__global__ __launch_bounds__(256) void k_fi(const float* __restrict__ w1,
                                            const float* __restrict__ b1,
                                            const float* __restrict__ g,
                                            const float* __restrict__ be,
                                            const float* __restrict__ w2,
                                            const float* __restrict__ b2f,
                                            float* __restrict__ ws){
  __shared__ float w1s[64][65];
  __shared__ float xs[4][64];
  int wv = threadIdx.x >> 6, lane = threadIdx.x & 63;
  for (int q = threadIdx.x; q < 4096; q += 256) w1s[q >> 6][q & 63] = w1[q];
  __syncthreads();
  const float* fe3 = ws + OFF_FE3;
  const float* st = ws + OFF_STATS;
  const float NinvG = 1.f/1048576.f;
  float mun = st[0]*NinvG, varn = st[1]*NinvG - mun*mun;
  float rsn = rsqrtf(varn + 1e-5f);
  float muc = st[2]*NinvG, varc = st[3]*NinvG - muc*muc;
  float rsc = rsqrtf(varc + 1e-5f);
  float b1l = b1[lane], gl = g[lane], bel = be[lane], w2l = w2[lane], b2s = b2f[0];
  int gw = blockIdx.x*4 + wv;                        // 0..4095
  float ls = 0.f, lss = 0.f;
  for (int it = 0; it < 8; ++it){
    int row = gw + 4096*it;                          // < 32768
    bool isn = (row & 31) < NNUM;
    float mu0 = isn ? mun : muc, rs0 = isn ? rsn : rsc;
    float x = (fe3[(size_t)row*64 + lane] - mu0)*rs0;
    xs[wv][lane] = x;
    float t0 = 0.f, t1 = 0.f, t2 = 0.f, t3 = 0.f;
    #pragma unroll
    for (int k = 0; k < 64; k += 4){
      float4 xq = *(const float4*)&xs[wv][k];
      t0 += xq.x*w1s[k][lane];
      t1 += xq.y*w1s[k+1][lane];
      t2 += xq.z*w1s[k+2][lane];
      t3 += xq.w*w1s[k+3][lane];
    }
    float t = (t0+t1) + (t2+t3) + b1l;
    t = fmaxf(t, 0.f);
    float mu = wsum64(t)*(1.f/64.f);
    float d = t - mu;
    float var = wsum64(d*d)*(1.f/64.f);
    float rs = rsqrtf(var + 1e-5f);
    float h1 = d*rs*gl + bel;
    float s = wsum64(h1*w2l) + b2s;                  // uniform across wave
    if (lane == 0) ws[OFF_SIMP + row] = s;
    ls += s; lss += s*s;
  }
  __shared__ float sh[8];
  if (lane == 0){ sh[wv] = ls; sh[4+wv] = lss; }
  __syncthreads();
  if (threadIdx.x == 0){
    atomicAdd(ws + OFF_STATS + 4, sh[0]+sh[1]+sh[2]+sh[3]);
    atomicAdd(ws + OFF_STATS + 5, sh[4]+sh[5]+sh[6]+sh[7]);
  }
}

// ---- K5: LN(imp), top-8, softmax p; fe3 = (raw-mu)*rs*imp (norm folded) ----
__global__ __launch_bounds__(256) void k_topk(float* __restrict__ ws){
  int b = blockIdx.x;
  __shared__ float imp[CC];
  if (threadIdx.x < CC){
    const float Ninv = 1.f/32768.f;
    float s4 = ws[OFF_STATS+4], s5 = ws[OFF_STATS+5];
    float mu = s4*Ninv, var = s5*Ninv - mu*mu;
    float rs = rsqrtf(var + 1e-5f);
    imp[threadIdx.x] = (ws[OFF_SIMP + b*CC + threadIdx.x] - mu)*rs;
  }
  __syncthreads();
  if (threadIdx.x == 0){
    unsigned taken = 0;
    float m0 = 0.f;
    for (int t = 0; t < KK; t++){
      float best = -1e30f; int bi = 0;
      for (int c = 0; c < CC; c++){
        if (!((taken >> c) & 1u) && imp[c] > best){ best = imp[c]; bi = c; }
      }
      taken |= 1u << bi;
      if (t == 0) m0 = best;
    }
    float sum = 0.f;
    int* cols = (int*)(ws + OFF_COLS);
    int tn = 0;
    for (int c = 0; c < CC; c++){
      if ((taken >> c) & 1u){ cols[b*KK + tn] = c; tn++; sum += expf(imp[c] - m0); }
    }
    float inv = 1.f/sum;
    for (int c = 0; c < CC; c++){
      float pv = ((taken >> c) & 1u) ? expf(imp[c] - m0)*inv : 0.f;
      ws[OFF_P + b*CC + c] = pv;
    }
  }
  __syncthreads();
  float* fe3 = ws + OFF_FE3;
  const float* st = ws + OFF_STATS;
  const float NinvG = 1.f/1048576.f;
  float mun = st[0]*NinvG, varn = st[1]*NinvG - mun*mun;
  float rsn = rsqrtf(varn + 1e-5f);
  float muc = st[2]*NinvG, varc = st[3]*NinvG - muc*muc;
  float rsc = rsqrtf(varc + 1e-5f);
  for (int q4 = threadIdx.x; q4 < 512; q4 += 256){
    int c = q4 >> 4;
    float mu, rs;
    if (c < NNUM){ mu = mun; rs = rsn; } else { mu = muc; rs = rsc; }
    float im = imp[c]*rs;
    float4 v = *(float4*)&fe3[b*CH + q4*4];
    v.x = (v.x - mu)*im; v.y = (v.y - mu)*im;
    v.z = (v.z - mu)*im; v.w = (v.w - mu)*im;
    *(float4*)&fe3[b*CH + q4*4] = v;
  }
}

// ---- K6: build per-channel row lists ---------------------------------------
__global__ __launch_bounds__(256) void k_lists(float* __restrict__ ws){
  int c = blockIdx.x;
  __shared__ int cnt_s;
  if (threadIdx.x == 0) cnt_s = 0;
  __syncthreads();
  int* list = (int*)(ws + OFF_LIST);
  for (int b = threadIdx.x; b < BB; b += 256){
    if (ws[OFF_P + b*CC + c] > 0.f){
      int slot = atomicAdd(&cnt_s, 1);
      list[c*BB + slot] = b;
    }
  }
  __syncthreads();
  if (threadIdx.x == 0) ((int*)(ws + OFF_CNT))[c] = cnt_s;
}

// ---- K6b: prefix offsets for compact An ------------------------------------
__global__ void k_offs(float* __restrict__ ws){
  if (threadIdx.x == 0){
    const int* cnt = (const int*)(ws + OFF_CNT);
    int* aoff = (int*)(ws + OFF_AOFF);
    int acc = 0;
    for (int c = 0; c < CC; c++){ aoff[c] = acc; acc += cnt[c]*cnt[c]; }
    aoff[CC] = acc;
  }
}

// ---- K7: G = feat @ gcn1_w, 16 rows/block, K chunked x512 in LDS -----------
// Each w1g load feeds 4 rows (4 FMA) -> 4x less weight traffic than 1-row/wave.
__global__ __launch_bounds__(256) void k_G(const float* __restrict__ w1g, float* __restrict__ ws){
  __shared__ float rs_[16][516];
  int wv = threadIdx.x >> 6, lane = threadIdx.x & 63;
  int b0 = blockIdx.x*16;                               // grid 64
  const float* fe3 = ws + OFF_FE3;
  float acc[4] = {0.f,0.f,0.f,0.f};
  for (int kc = 0; kc < CH; kc += 512){
    __syncthreads();
    #pragma unroll
    for (int s = 0; s < 8; s++){
      int slot = threadIdx.x + s*256;                   // 2048 float4 slots
      int r = slot >> 7, q = slot & 127;
      float4 v = *(const float4*)&fe3[(size_t)(b0 + r)*CH + kc + q*4];
      *(float4*)&rs_[r][q*4] = v;
    }
    __syncthreads();
    int rbase = wv*4;
    for (int k = 0; k < 512; k += 4){
      float wa = w1g[(size_t)(kc+k+0)*64 + lane];
      float wb = w1g[(size_t)(kc+k+1)*64 + lane];
      float wc = w1g[(size_t)(kc+k+2)*64 + lane];
      float wd = w1g[(size_t)(kc+k+3)*64 + lane];
      #pragma unroll
      for (int r = 0; r < 4; r++){
        float4 f = *(const float4*)&rs_[rbase + r][k];
        acc[r] += f.x*wa + f.y*wb + f.z*wc + f.w*wd;
      }
    }
  }
  #pragma unroll
  for (int r = 0; r < 4; r++)
    ws[OFF_G + (size_t)(b0 + wv*4 + r)*64 + lane] = acc[r];
}

// ---- K8: E matrix + rowE + Z, LDS-tiled (R8-proven) ------------------------
__global__ __launch_bounds__(256) void k_E(float* __restrict__ ws){
  int c = blockIdx.x;
  int n = ((const int*)(ws + OFF_CNT))[c];
  int r0 = blockIdx.y*32;                               // gridDim.y = 32
  if (r0 >= n) return;
  const int* list = (const int*)(ws + OFF_LIST) + c*BB;
  const float* p = ws + OFF_P;
  int base = ((const int*)(ws + OFF_AOFF))[c];
  float* An = ws + OFF_AN;
  __shared__ float pis[32][36];
  __shared__ float pT[32][72];
  int wv = threadIdx.x >> 6, lane = threadIdx.x & 63;
  for (int idx = threadIdx.x; idx < 1024; idx += 256){
    int r = idx >> 5, u = idx & 31;
    int ii = r0 + r;
    float v = 0.f;
    if (ii < n && u != c) v = p[list[ii]*CC + u];
    pis[r][u] = v;
  }
  float re[8] = {0.f,0.f,0.f,0.f,0.f,0.f,0.f,0.f};
  int rowBase = r0 + wv*8;
  for (int jt = 0; jt < n; jt += 64){
    __syncthreads();
    for (int idx = threadIdx.x; idx < 2048; idx += 256){
      int t = idx & 63, u = idx >> 6;
      int jj = jt + t;
      float v = 0.f;
      if (jj < n) v = p[list[jj]*CC + u];
      pT[u][t] = v;
    }
    __syncthreads();
    int jj = jt + lane;
    bool jok = (jj < n);
    #pragma unroll
    for (int r = 0; r < 8; r++){
      int row = rowBase + r;
      if (row < n){
        float4 pi0 = *(const float4*)&pis[wv*8 + r][0];
        float4 pi1 = *(const float4*)&pis[wv*8 + r][4];
        float4 pi2 = *(const float4*)&pis[wv*8 + r][8];
        float4 pi3 = *(const float4*)&pis[wv*8 + r][12];
        float4 pi4 = *(const float4*)&pis[wv*8 + r][16];
        float4 pi5 = *(const float4*)&pis[wv*8 + r][20];
        float4 pi6 = *(const float4*)&pis[wv*8 + r][24];
        float4 pi7 = *(const float4*)&pis[wv*8 + r][28];
        float s0 = pi0.x*pT[0][lane]  + pi1.x*pT[4][lane]  + pi2.x*pT[8][lane]  + pi3.x*pT[12][lane]
                 + pi4.x*pT[16][lane] + pi5.x*pT[20][lane] + pi6.x*pT[24][lane] + pi7.x*pT[28][lane];
        float s1 = pi0.y*pT[1][lane]  + pi1.y*pT[5][lane]  + pi2.y*pT[9][lane]  + pi3.y*pT[13][lane]
                 + pi4.y*pT[17][lane] + pi5.y*pT[21][lane] + pi6.y*pT[25][lane] + pi7.y*pT[29][lane];
        float s2 = pi0.z*pT[2][lane]  + pi1.z*pT[6][lane]  + pi2.z*pT[10][lane] + pi3.z*pT[14][lane]
                 + pi4.z*pT[18][lane] + pi5.z*pT[22][lane] + pi6.z*pT[26][lane] + pi7.z*pT[30][lane];
        float s3 = pi0.w*pT[3][lane]  + pi1.w*pT[7][lane]  + pi2.w*pT[11][lane] + pi3.w*pT[15][lane]
                 + pi4.w*pT[19][lane] + pi5.w*pT[23][lane] + pi6.w*pT[27][lane] + pi7.w*pT[31][lane];
        float S = (s0+s1) + (s2+s3);
        float Ev = 0.f;
        if (jok && jj != row && S > 0.f) Ev = __expf(S);
        if (jok) An[(size_t)base + (size_t)row*n + jj] = Ev;
        re[r] += Ev;
      }
    }
  }
  float zpart = 0.f;
  #pragma unroll
  for (int r = 0; r < 8; r++){
    float rsum = wsum64(re[r]);
    int row = rowBase + r;
    if (lane == 0 && row < n){
      ws[OFF_ROWE + c*BB + row] = rsum;
      zpart += rsum;
    }
  }
  __shared__ float sh[4];
  if (lane == 0) sh[wv] = zpart;
  __syncthreads();
  if (threadIdx.x == 0) atomicAdd(ws + OFF_Z + c, sh[0]+sh[1]+sh[2]+sh[3]);
}

// ---- K9: dpos = rsqrt(rowE/Z' + 1), fpos = dpos/sqrt(Z') -------------------
__global__ __launch_bounds__(256) void k_scl(float* __restrict__ ws){
  int c = blockIdx.x;
  int n = ((const int*)(ws + OFF_CNT))[c];
  int ii = blockIdx.y*256 + threadIdx.x;                // gridDim.y = 4
  if (ii >= n) return;
  float z = ws[OFF_Z + c];
  float zp = (z > 0.f) ? z : 1.f;
  float re = ws[OFF_ROWE + c*BB + ii];
  float di = rsqrtf(re/zp + 1.0f);
  ws[OFF_DINV + c*BB + ii] = di;
  ws[OFF_F    + c*BB + ii] = di*rsqrtf(zp);
}

// ---- K11: aggregation v5 (best measured) -- LDS-only inner loop ------------
__global__ __launch_bounds__(256) void k_agg(const float* __restrict__ src, int chanStride,
                                             const float* __restrict__ bias,
                                             float* __restrict__ outb,
                                             float* __restrict__ statsb,
                                             float* __restrict__ ws){
  int c = blockIdx.x;
  int n = ((const int*)(ws + OFF_CNT))[c];
  int r0 = blockIdx.y*16;                               // gridDim.y = 64
  if (r0 >= n) return;
  int base = ((const int*)(ws + OFF_AOFF))[c];
  const int* lst = (const int*)(ws + OFF_LIST) + c*BB;
  const float* E = ws + OFF_AN + (size_t)base;
  const float* fpos = ws + OFF_F + c*BB;
  const float* dpos = ws + OFF_DINV + c*BB;
  const float* srcc = src + (size_t)c*(size_t)chanStride*64;
  __shared__ float cf[16][128];
  __shared__ float sl[128][64];
  __shared__ float frow_s[16];
  int wv = threadIdx.x >> 6, lane = threadIdx.x & 63;
  if (threadIdx.x < 16){
    int rr = r0 + threadIdx.x;
    frow_s[threadIdx.x] = (rr < n) ? fpos[rr] : 0.f;
  }
  int rw = wv*4;
  float acc[4] = {0.f,0.f,0.f,0.f};
  for (int jt = 0; jt < n; jt += 128){
    __syncthreads();
    #pragma unroll
    for (int s = 0; s < 8; s++){
      int slot = threadIdx.x + s*256;
      int j = slot >> 4, q = slot & 15;
      int jj = jt + j;
      float4 v = make_float4(0.f,0.f,0.f,0.f);
      if (jj < n){
        int jg = lst[jj];
        v = *(const float4*)&srcc[(size_t)jg*64 + q*4];
      }
      *(float4*)&sl[j][q*4] = v;
    }
    #pragma unroll
    for (int s = 0; s < 8; s++){
      int idx = threadIdx.x + s*256;
      int r = idx >> 7, j = idx & 127;
      int row = r0 + r, jj = jt + j;
      float v = 0.f;
      if (row < n && jj < n){
        if (jj == row){ float d = dpos[row]; v = d*d; }
        else v = E[(size_t)row*n + jj] * fpos[jj] * frow_s[r];
      }
      cf[r][j] = v;
    }
    __syncthreads();
    int jcnt = n - jt; if (jcnt > 128) jcnt = 128;
    int jcnt4 = (jcnt + 3) & ~3;
    for (int j = 0; j < jcnt4; j += 4){
      float v0 = sl[j+0][lane];
      float v1 = sl[j+1][lane];
      float v2 = sl[j+2][lane];
      float v3 = sl[j+3][lane];
      #pragma unroll
      for (int r = 0; r < 4; r++){
        float4 c4 = *(const float4*)&cf[rw + r][j];
        acc[r] += c4.x*v0 + c4.y*v1 + c4.z*v2 + c4.w*v3;
      }
    }
  }
  float bl = bias[lane];
  float s = 0.f, ssq = 0.f;
  #pragma unroll
  for (int r = 0; r < 4; r++){
    int row = r0 + rw + r;
    if (row < n){
      float a = fmaxf(acc[r] + bl, 0.f);
      outb[((size_t)c*BB + lst[row])*64 + lane] = a;
      s += a; ssq += a*a;
    }
  }
  s = wsum64(s); ssq = wsum64(ssq);
  __shared__ float shs[4], shq[4];
  if (lane == 0){ shs[wv] = s; shq[wv] = ssq; }
  __syncthreads();
  if (threadIdx.x == 0){
    float ts = shs[0]+shs[1]+shs[2]+shs[3];
    float tq = shq[0]+shq[1]+shq[2]+shq[3];
    if (tq != 0.f){
      atomicAdd(statsb + 2*c,     ts);
      atomicAdd(statsb + 2*c + 1, tq);
    }
  }
}

// ---- K12: x1n = masked_ln(x1); y = x1n @ gcn2_w (in place over x1) ---------
__global__ __launch_bounds__(256) void k_y(const float* __restrict__ w2g, float* __restrict__ ws){
  __shared__ float w2s[64][65];
  __shared__ float xs[4][64];
  int wv = threadIdx.x >> 6, lane = threadIdx.x & 63;
  for (int q = threadIdx.x; q < 4096; q += 256) w2s[q >> 6][q & 63] = w2g[q];
  __syncthreads();
  int c = blockIdx.x;
  int n = ((const int*)(ws + OFF_CNT))[c];
  const int* list = (const int*)(ws + OFF_LIST);
  float* x1 = ws + OFF_X1;
  float cntf = fmaxf((float)(n*64), 1.f);
  float mu = ws[OFF_X1S + 2*c]/cntf;
  float var = ws[OFF_X1S + 2*c + 1]/cntf - mu*mu;
  float rs = rsqrtf(var + 1e-5f);
  for (int ii = blockIdx.y*4 + wv; ii < n; ii += 64){   // gridDim.y = 16
    int i = list[c*BB + ii];
    size_t bse = ((size_t)c*BB + i)*64;
    float xn = (x1[bse + lane] - mu)*rs;
    xs[wv][lane] = xn;
    float y0 = 0.f, y1 = 0.f, y2 = 0.f, y3 = 0.f;
    #pragma unroll
    for (int k = 0; k < 64; k += 4){
      float4 xq = *(const float4*)&xs[wv][k];
      y0 += xq.x*w2s[k][lane];
      y1 += xq.y*w2s[k+1][lane];
      y2 += xq.z*w2s[k+2][lane];
      y3 += xq.w*w2s[k+3][lane];
    }
    x1[bse + lane] = (y0+y1) + (y2+y3);
  }
}

// ---- K13: final head, 16 rows/block, K chunked x512 in LDS -----------------
__global__ __launch_bounds__(256) void k_final(const float* __restrict__ pw1,
                                               const float* __restrict__ pb1,
                                               const float* __restrict__ pg,
                                               const float* __restrict__ pbe,
                                               const float* __restrict__ pw2,
                                               const float* __restrict__ pb2,
                                               float* __restrict__ ws,
                                               float* __restrict__ out){
  __shared__ float ck[16][516];
  __shared__ float nf[CC][2];
  __shared__ int cols_s[16][8];
  int wv = threadIdx.x >> 6, lane = threadIdx.x & 63;
  int b0 = blockIdx.x*16;                               // grid 64
  const int* cols = (const int*)(ws + OFF_COLS);
  const int* cnt  = (const int*)(ws + OFF_CNT);
  const float* x2 = ws + OFF_X2;
  const float* fe3 = ws + OFF_FE3;
  if (threadIdx.x < 32){
    int ct = threadIdx.x;
    float cf = fmaxf((float)(cnt[ct]*64), 1.f);
    float mu = ws[OFF_X2S + 2*ct]/cf;
    float var = ws[OFF_X2S + 2*ct + 1]/cf - mu*mu;
    nf[ct][0] = mu; nf[ct][1] = rsqrtf(var + 1e-5f);
  }
  if (threadIdx.x < 128){
    int r = threadIdx.x >> 3, t = threadIdx.x & 7;
    cols_s[r][t] = cols[(b0 + r)*KK + t];
  }
  float acc[4] = {0.f,0.f,0.f,0.f};
  for (int kc = 0; kc < FULLW; kc += 512){
    __syncthreads();
    if (kc == 0){
      // gathered + masked-LN'd x2: 2048 float4 slots
      #pragma unroll
      for (int s = 0; s < 8; s++){
        int slot = threadIdx.x + s*256;
        int r = slot >> 7, q = slot & 127;
        int t = q >> 4, h4 = q & 15;
        int ct = cols_s[r][t];
        float mu = nf[ct][0], rsv = nf[ct][1];
        float4 v = *(const float4*)&x2[((size_t)ct*BB + b0 + r)*64 + h4*4];
        v.x = (v.x - mu)*rsv; v.y = (v.y - mu)*rsv;
        v.z = (v.z - mu)*rsv; v.w = (v.w - mu)*rsv;
        *(float4*)&ck[r][q*4] = v;
      }
    } else {
      #pragma unroll
      for (int s = 0; s < 8; s++){
        int slot = threadIdx.x + s*256;
        int r = slot >> 7, q = slot & 127;
        float4 v = *(const float4*)&fe3[(size_t)(b0 + r)*CH + (kc - 512) + q*4];
        *(float4*)&ck[r][q*4] = v;
      }
    }
    __syncthreads();
    int rbase = wv*4;
    for (int k = 0; k < 512; k += 4){
      float wa = pw1[(size_t)(kc+k+0)*64 + lane];
      float wb = pw1[(size_t)(kc+k+1)*64 + lane];
      float wc = pw1[(size_t)(kc+k+2)*64 + lane];
      float wd = pw1[(size_t)(kc+k+3)*64 + lane];
      #pragma unroll
      for (int r = 0; r < 4; r++){
        float4 f = *(const float4*)&ck[rbase + r][k];
        acc[r] += f.x*wa + f.y*wb + f.z*wc + f.w*wd;
      }
    }
  }
  float bl = pb1[lane], gl = pg[lane], bel = pbe[lane];
  float w20 = pw2[lane*2 + 0], w21 = pw2[lane*2 + 1];
  float o0 = pb2[0], o1 = pb2[1];
  #pragma unroll
  for (int r = 0; r < 4; r++){
    int b = b0 + wv*4 + r;
    float a = fmaxf(acc[r] + bl, 0.f);
    float mu = wsum64(a)*(1.f/64.f);
    float d = a - mu;
    float var = wsum64(d*d)*(1.f/64.f);
    float rs = rsqrtf(var + 1e-5f);
    float zn = d*rs*gl + bel;
    float s0 = wsum64(zn*w20);
    float s1 = wsum64(zn*w21);
    if (lane == 0){
      out[b*2 + 0] = s0 + o0;
      out[b*2 + 1] = s1 + o1;
    }
  }
}

extern "C" void kernel_launch(void* const* d_in, const int* in_sizes, int n_in,
                              void* d_out, int out_size, void* d_ws, size_t ws_size,
                              hipStream_t stream){
  (void)in_sizes; (void)n_in; (void)out_size; (void)ws_size;
  const float* num_data = (const float*)d_in[0];
  const int*   cat_data = (const int*)d_in[1];
  const float* num_w   = (const float*)d_in[2];
  const float* num_b   = (const float*)d_in[3];
  const float* cat_emb = (const float*)d_in[4];
  const float* fi_w1   = (const float*)d_in[5];
  const float* fi_b1   = (const float*)d_in[6];
  const float* fi_g    = (const float*)d_in[7];
  const float* fi_be   = (const float*)d_in[8];
  const float* fi_w2   = (const float*)d_in[9];
  const float* fi_b2   = (const float*)d_in[10];
  const float* gcn1_w  = (const float*)d_in[11];
  const float* gcn1_b  = (const float*)d_in[12];
  const float* gcn2_w  = (const float*)d_in[13];
  const float* gcn2_b  = (const float*)d_in[14];
  const float* pw1     = (const float*)d_in[15];
  const float* pb1     = (const float*)d_in[16];
  const float* pg      = (const float*)d_in[17];
  const float* pbe     = (const float*)d_in[18];
  const float* pw2     = (const float*)d_in[19];
  const float* pb2     = (const float*)d_in[20];
  float* ws  = (float*)d_ws;
  float* out = (float*)d_out;

  k_init<<<1, 256, 0, stream>>>(ws);
  k_fe<<<2048, 256, 0, stream>>>(num_data, num_w, num_b, cat_data, cat_emb, ws);
  k_fi<<<1024, 256, 0, stream>>>(fi_w1, fi_b1, fi_g, fi_be, fi_w2, fi_b2, ws);
  k_topk<<<1024, 256, 0, stream>>>(ws);
  k_lists<<<32, 256, 0, stream>>>(ws);
  k_offs<<<1, 64, 0, stream>>>(ws);
  k_G<<<64, 256, 0, stream>>>(gcn1_w, ws);
  k_E<<<dim3(32, 32), 256, 0, stream>>>(ws);
  k_scl<<<dim3(32, 4), 256, 0, stream>>>(ws);
  k_agg<<<dim3(32, 64), 256, 0, stream>>>(ws + OFF_G, 0, gcn1_b, ws + OFF_X1, ws + OFF_X1S, ws);
  k_y<<<dim3(32, 16), 256, 0, stream>>>(gcn2_w, ws);
  k_agg<<<dim3(32, 64), 256, 0, stream>>>(ws + OFF_X1, BB, gcn2_b, ws + OFF_X2, ws + OFF_X2S, ws);
  k_final<<<64, 256, 0, stream>>>(pw1, pb1, pg, pbe, pw2, pb2, ws, out);
}

// Round 12
// 524.832 us; speedup vs baseline: 1.5179x; 1.5179x over previous
//
#include <hip/hip_runtime.h>
#include <hip/hip_bf16.h>

#define BB   1024
#define NNUM 16
#define NCAT 16
#define HH   64
#define VV   100
#define KK   8
#define CC   32
#define CH   2048      // C*H
#define FULLW 2560     // (K+C)*H

// workspace offsets (in floats)
#define OFF_FE3   0u
#define OFF_X1    2097152u
#define OFF_X2    4194304u
#define OFF_G     6291456u   // feat @ gcn1_w  (B x H)
#define OFF_SIMP  6356992u   // raw s (B*C)
#define OFF_P     6389760u   // p dense (B*C)
#define OFF_ROWE  6422528u   // rowE, position-indexed [c][ii]
#define OFF_DINV  6455296u   // dpos = dinv, position-indexed [c][ii]
#define OFF_F     6488064u   // fpos = dinv/sqrt(Z'), position-indexed [c][ii]
#define OFF_STATS 6520832u   // [0,1]=num sum/ssq [2,3]=cat [4,5]=imp
#define OFF_Z     6520840u   // per-channel Z (C)
#define OFF_X1S   6520872u   // per-channel sum/ssq of relu(x1) (2C)
#define OFF_X2S   6520936u   // per-channel sum/ssq of relu(x2) (2C)
#define OFF_COLS  6521000u   // int: sorted top-k indices (B*K)
#define OFF_LIST  6529192u   // int: per-channel row lists (C*B)
#define OFF_CNT   6561960u   // int: per-channel counts (C)
#define OFF_AOFF  6561992u   // int: prefix offsets of n_c^2 (C+1)
#define OFF_AN    6562048u   // compact E matrices, worst 8388608 floats

__device__ inline float wsum64(float v){
  #pragma unroll
  for (int o = 32; o; o >>= 1) v += __shfl_xor(v, o);
  return v;
}

// ---- K0: zero the atomic accumulators --------------------------------------
__global__ __launch_bounds__(256) void k_init(float* ws){
  int t = threadIdx.x;
  if (t < 8)  ws[OFF_STATS + t] = 0.f;
  if (t < 64) ws[OFF_X1S + t] = 0.f;
  if (t < 64) ws[OFF_X2S + t] = 0.f;
  if (t < 32) ws[OFF_Z + t] = 0.f;
}

// ---- K1: fused fe_num + fe_cat RAW (float4/thread), stats accumulated ------
__global__ __launch_bounds__(256) void k_fe(const float* __restrict__ nd,
                                            const float* __restrict__ nw,
                                            const float* __restrict__ nb,
                                            const int* __restrict__ cd,
                                            const float* __restrict__ emb,
                                            float* __restrict__ ws){
  float* fe3 = ws + OFF_FE3;
  float lsn = 0.f, lssn = 0.f, lsc = 0.f, lssc = 0.f;
  int idx = blockIdx.x*256 + threadIdx.x;          // < 524288 (2048 blocks)
  {
    int h4 = idx & 15, fn = (idx >> 4) & 15, b = (idx >> 8) & 1023;
    bool isNum = (idx < 262144);
    if (isNum){
      float s = nd[b*NNUM + fn];
      float4 w = *(const float4*)&nw[fn*HH + h4*4];
      float4 bi = *(const float4*)&nb[fn*HH + h4*4];
      float4 v;
      v.x = fmaxf(s*w.x + bi.x, 0.f);
      v.y = fmaxf(s*w.y + bi.y, 0.f);
      v.z = fmaxf(s*w.z + bi.z, 0.f);
      v.w = fmaxf(s*w.w + bi.w, 0.f);
      *(float4*)&fe3[b*CH + fn*HH + h4*4] = v;
      lsn = v.x+v.y+v.z+v.w;
      lssn = v.x*v.x+v.y*v.y+v.z*v.z+v.w*v.w;
    } else {
      int j = cd[b*NCAT + fn];
      float4 v = *(const float4*)&emb[((size_t)fn*VV + j)*HH + h4*4];
      *(float4*)&fe3[b*CH + (NNUM + fn)*HH + h4*4] = v;
      lsc = v.x+v.y+v.z+v.w;
      lssc = v.x*v.x+v.y*v.y+v.z*v.z+v.w*v.w;
    }
  }
  __shared__ float sh[16];
  lsn = wsum64(lsn); lssn = wsum64(lssn);
  lsc = wsum64(lsc); lssc = wsum64(lssc);
  int w = threadIdx.x >> 6;
  if ((threadIdx.x & 63) == 0){ sh[w] = lsn; sh[4+w] = lssn; sh[8+w] = lsc; sh[12+w] = lssc; }
  __syncthreads();
  if (threadIdx.x == 0){
    if (blockIdx.x < 1024){
      atomicAdd(ws + OFF_STATS + 0, sh[0]+sh[1]+sh[2]+sh[3]);
      atomicAdd(ws + OFF_STATS + 1, sh[4]+sh[5]+sh[6]+sh[7]);
    } else {
      atomicAdd(ws + OFF_STATS + 2, sh[8]+sh[9]+sh[10]+sh[11]);
      atomicAdd(ws + OFF_STATS + 3, sh[12]+sh[13]+sh[14]+sh[15]);
    }
  }
}

// ---- K4: feature-importance head (normalizes raw fe3 on the fly) -----------
__global__ __launch_bounds__(256) void k_fi(const float* __restrict__ w1,
                                            const float* __restrict__ b1,
                                            const float* __restrict__ g,
                                            const float* __restrict__ be,
                                            const float* __restrict__ w2,
                                            const float* __restrict__ b2f,
                                            float* __restrict__ ws){
  __shared__ float w1s[64][65];
  __shared__ float xs[4][64];
  int wv = threadIdx.x >> 6, lane = threadIdx.x & 63;
  for (int q = threadIdx.x; q < 4096; q += 256) w1s[q >> 6][q & 63] = w1[q];
  __syncthreads();
  const float* fe3 = ws + OFF_FE3;
  const float* st = ws + OFF_STATS;
  const float NinvG = 1.f/1048576.f;
  float mun = st[0]*NinvG, varn = st[1]*NinvG - mun*mun;
  float rsn = rsqrtf(varn + 1e-5f);
  float muc = st[2]*NinvG, varc = st[3]*NinvG - muc*muc;
  float rsc = rsqrtf(varc + 1e-5f);
  float b1l = b1[lane], gl = g[lane], bel = be[lane], w2l = w2[lane], b2s = b2f[0];
  int gw = blockIdx.x*4 + wv;                        // 0..4095
  float ls = 0.f, lss = 0.f;
  for (int it = 0; it < 8; ++it){
    int row = gw + 4096*it;                          // < 32768
    bool isn = (row & 31) < NNUM;
    float mu0 = isn ? mun : muc, rs0 = isn ? rsn : rsc;
    float x = (fe3[(size_t)row*64 + lane] - mu0)*rs0;
    xs[wv][lane] = x;
    float t0 = 0.f, t1 = 0.f, t2 = 0.f, t3 = 0.f;
    #pragma unroll
    for (int k = 0; k < 64; k += 4){
      float4 xq = *(const float4*)&xs[wv][k];
      t0 += xq.x*w1s[k][lane];
      t1 += xq.y*w1s[k+1][lane];
      t2 += xq.z*w1s[k+2][lane];
      t3 += xq.w*w1s[k+3][lane];
    }
    float t = (t0+t1) + (t2+t3) + b1l;
    t = fmaxf(t, 0.f);
    float mu = wsum64(t)*(1.f/64.f);
    float d = t - mu;
    float var = wsum64(d*d)*(1.f/64.f);
    float rs = rsqrtf(var + 1e-5f);
    float h1 = d*rs*gl + bel;
    float s = wsum64(h1*w2l) + b2s;                  // uniform across wave
    if (lane == 0) ws[OFF_SIMP + row] = s;
    ls += s; lss += s*s;
  }
  __shared__ float sh[8];
  if (lane == 0){ sh[wv] = ls; sh[4+wv] = lss; }
  __syncthreads();
  if (threadIdx.x == 0){
    atomicAdd(ws + OFF_STATS + 4, sh[0]+sh[1]+sh[2]+sh[3]);
    atomicAdd(ws + OFF_STATS + 5, sh[4]+sh[5]+sh[6]+sh[7]);
  }
}

// ---- K5: LN(imp), top-8, softmax p; fe3 = (raw-mu)*rs*imp (norm folded) ----
__global__ __launch_bounds__(256) void k_topk(float* __restrict__ ws){
  int b = blockIdx.x;
  __shared__ float imp[CC];
  if (threadIdx.x < CC){
    const float Ninv = 1.f/32768.f;
    float s4 = ws[OFF_STATS+4], s5 = ws[OFF_STATS+5];
    float mu = s4*Ninv, var = s5*Ninv - mu*mu;
    float rs = rsqrtf(var + 1e-5f);
    imp[threadIdx.x] = (ws[OFF_SIMP + b*CC + threadIdx.x] - mu)*rs;
  }
  __syncthreads();
  if (threadIdx.x == 0){
    unsigned taken = 0;
    float m0 = 0.f;
    for (int t = 0; t < KK; t++){
      float best = -1e30f; int bi = 0;
      for (int c = 0; c < CC; c++){
        if (!((taken >> c) & 1u) && imp[c] > best){ best = imp[c]; bi = c; }
      }
      taken |= 1u << bi;
      if (t == 0) m0 = best;
    }
    float sum = 0.f;
    int* cols = (int*)(ws + OFF_COLS);
    int tn = 0;
    for (int c = 0; c < CC; c++){
      if ((taken >> c) & 1u){ cols[b*KK + tn] = c; tn++; sum += expf(imp[c] - m0); }
    }
    float inv = 1.f/sum;
    for (int c = 0; c < CC; c++){
      float pv = ((taken >> c) & 1u) ? expf(imp[c] - m0)*inv : 0.f;
      ws[OFF_P + b*CC + c] = pv;
    }
  }
  __syncthreads();
  float* fe3 = ws + OFF_FE3;
  const float* st = ws + OFF_STATS;
  const float NinvG = 1.f/1048576.f;
  float mun = st[0]*NinvG, varn = st[1]*NinvG - mun*mun;
  float rsn = rsqrtf(varn + 1e-5f);
  float muc = st[2]*NinvG, varc = st[3]*NinvG - muc*muc;
  float rsc = rsqrtf(varc + 1e-5f);
  for (int q4 = threadIdx.x; q4 < 512; q4 += 256){
    int c = q4 >> 4;
    float mu, rs;
    if (c < NNUM){ mu = mun; rs = rsn; } else { mu = muc; rs = rsc; }
    float im = imp[c]*rs;
    float4 v = *(float4*)&fe3[b*CH + q4*4];
    v.x = (v.x - mu)*im; v.y = (v.y - mu)*im;
    v.z = (v.z - mu)*im; v.w = (v.w - mu)*im;
    *(float4*)&fe3[b*CH + q4*4] = v;
  }
}

// ---- K6: build per-channel row lists ---------------------------------------
__global__ __launch_bounds__(256) void k_lists(float* __restrict__ ws){
  int c = blockIdx.x;
  __shared__ int cnt_s;
  if (threadIdx.x == 0) cnt_s = 0;
  __syncthreads();
  int* list = (int*)(ws + OFF_LIST);
  for (int b = threadIdx.x; b < BB; b += 256){
    if (ws[OFF_P + b*CC + c] > 0.f){
      int slot = atomicAdd(&cnt_s, 1);
      list[c*BB + slot] = b;
    }
  }
  __syncthreads();
  if (threadIdx.x == 0) ((int*)(ws + OFF_CNT))[c] = cnt_s;
}

// ---- K6b: prefix offsets for compact An ------------------------------------
__global__ void k_offs(float* __restrict__ ws){
  if (threadIdx.x == 0){
    const int* cnt = (const int*)(ws + OFF_CNT);
    int* aoff = (int*)(ws + OFF_AOFF);
    int acc = 0;
    for (int c = 0; c < CC; c++){ aoff[c] = acc; acc += cnt[c]*cnt[c]; }
    aoff[CC] = acc;
  }
}

// ---- K7: G = feat @ gcn1_w (R9-proven: 256 blocks, 1 row/wave) -------------
__global__ __launch_bounds__(256) void k_G(const float* __restrict__ w1g, float* __restrict__ ws){
  __shared__ float frow[4][CH];
  int wv = threadIdx.x >> 6, lane = threadIdx.x & 63;
  int b = blockIdx.x*4 + wv;
  const float* fe3 = ws + OFF_FE3;
  for (int q = 0; q < 32; q++) frow[wv][q*64 + lane] = fe3[b*CH + q*64 + lane];
  __syncthreads();
  float a0 = 0.f, a1 = 0.f, a2 = 0.f, a3 = 0.f;
  #pragma unroll 8
  for (int k = 0; k < CH; k += 4){
    float4 fq = *(const float4*)&frow[wv][k];
    a0 += fq.x*w1g[(k+0)*64 + lane];
    a1 += fq.y*w1g[(k+1)*64 + lane];
    a2 += fq.z*w1g[(k+2)*64 + lane];
    a3 += fq.w*w1g[(k+3)*64 + lane];
  }
  ws[OFF_G + b*64 + lane] = (a0+a1) + (a2+a3);
}

// ---- K8: E matrix + rowE + Z, LDS-tiled (R8-proven) ------------------------
__global__ __launch_bounds__(256) void k_E(float* __restrict__ ws){
  int c = blockIdx.x;
  int n = ((const int*)(ws + OFF_CNT))[c];
  int r0 = blockIdx.y*32;                               // gridDim.y = 32
  if (r0 >= n) return;
  const int* list = (const int*)(ws + OFF_LIST) + c*BB;
  const float* p = ws + OFF_P;
  int base = ((const int*)(ws + OFF_AOFF))[c];
  float* An = ws + OFF_AN;
  __shared__ float pis[32][36];
  __shared__ float pT[32][72];
  int wv = threadIdx.x >> 6, lane = threadIdx.x & 63;
  for (int idx = threadIdx.x; idx < 1024; idx += 256){
    int r = idx >> 5, u = idx & 31;
    int ii = r0 + r;
    float v = 0.f;
    if (ii < n && u != c) v = p[list[ii]*CC + u];
    pis[r][u] = v;
  }
  float re[8] = {0.f,0.f,0.f,0.f,0.f,0.f,0.f,0.f};
  int rowBase = r0 + wv*8;
  for (int jt = 0; jt < n; jt += 64){
    __syncthreads();
    for (int idx = threadIdx.x; idx < 2048; idx += 256){
      int t = idx & 63, u = idx >> 6;
      int jj = jt + t;
      float v = 0.f;
      if (jj < n) v = p[list[jj]*CC + u];
      pT[u][t] = v;
    }
    __syncthreads();
    int jj = jt + lane;
    bool jok = (jj < n);
    #pragma unroll
    for (int r = 0; r < 8; r++){
      int row = rowBase + r;
      if (row < n){
        float4 pi0 = *(const float4*)&pis[wv*8 + r][0];
        float4 pi1 = *(const float4*)&pis[wv*8 + r][4];
        float4 pi2 = *(const float4*)&pis[wv*8 + r][8];
        float4 pi3 = *(const float4*)&pis[wv*8 + r][12];
        float4 pi4 = *(const float4*)&pis[wv*8 + r][16];
        float4 pi5 = *(const float4*)&pis[wv*8 + r][20];
        float4 pi6 = *(const float4*)&pis[wv*8 + r][24];
        float4 pi7 = *(const float4*)&pis[wv*8 + r][28];
        float s0 = pi0.x*pT[0][lane]  + pi1.x*pT[4][lane]  + pi2.x*pT[8][lane]  + pi3.x*pT[12][lane]
                 + pi4.x*pT[16][lane] + pi5.x*pT[20][lane] + pi6.x*pT[24][lane] + pi7.x*pT[28][lane];
        float s1 = pi0.y*pT[1][lane]  + pi1.y*pT[5][lane]  + pi2.y*pT[9][lane]  + pi3.y*pT[13][lane]
                 + pi4.y*pT[17][lane] + pi5.y*pT[21][lane] + pi6.y*pT[25][lane] + pi7.y*pT[29][lane];
        float s2 = pi0.z*pT[2][lane]  + pi1.z*pT[6][lane]  + pi2.z*pT[10][lane] + pi3.z*pT[14][lane]
                 + pi4.z*pT[18][lane] + pi5.z*pT[22][lane] + pi6.z*pT[26][lane] + pi7.z*pT[30][lane];
        float s3 = pi0.w*pT[3][lane]  + pi1.w*pT[7][lane]  + pi2.w*pT[11][lane] + pi3.w*pT[15][lane]
                 + pi4.w*pT[19][lane] + pi5.w*pT[23][lane] + pi6.w*pT[27][lane] + pi7.w*pT[31][lane];
        float S = (s0+s1) + (s2+s3);
        float Ev = 0.f;
        if (jok && jj != row && S > 0.f) Ev = __expf(S);
        if (jok) An[(size_t)base + (size_t)row*n + jj] = Ev;
        re[r] += Ev;
      }
    }
  }
  float zpart = 0.f;
  #pragma unroll
  for (int r = 0; r < 8; r++){
    float rsum = wsum64(re[r]);
    int row = rowBase + r;
    if (lane == 0 && row < n){
      ws[OFF_ROWE + c*BB + row] = rsum;
      zpart += rsum;
    }
  }
  __shared__ float sh[4];
  if (lane == 0) sh[wv] = zpart;
  __syncthreads();
  if (threadIdx.x == 0) atomicAdd(ws + OFF_Z + c, sh[0]+sh[1]+sh[2]+sh[3]);
}

// ---- K9: dpos = rsqrt(rowE/Z' + 1), fpos = dpos/sqrt(Z') -------------------
__global__ __launch_bounds__(256) void k_scl(float* __restrict__ ws){
  int c = blockIdx.x;
  int n = ((const int*)(ws + OFF_CNT))[c];
  int ii = blockIdx.y*256 + threadIdx.x;                // gridDim.y = 4
  if (ii >= n) return;
  float z = ws[OFF_Z + c];
  float zp = (z > 0.f) ? z : 1.f;
  float re = ws[OFF_ROWE + c*BB + ii];
  float di = rsqrtf(re/zp + 1.0f);
  ws[OFF_DINV + c*BB + ii] = di;
  ws[OFF_F    + c*BB + ii] = di*rsqrtf(zp);
}

// ---- K11: aggregation v5 (best measured) -- LDS-only inner loop ------------
__global__ __launch_bounds__(256) void k_agg(const float* __restrict__ src, int chanStride,
                                             const float* __restrict__ bias,
                                             float* __restrict__ outb,
                                             float* __restrict__ statsb,
                                             float* __restrict__ ws){
  int c = blockIdx.x;
  int n = ((const int*)(ws + OFF_CNT))[c];
  int r0 = blockIdx.y*16;                               // gridDim.y = 64
  if (r0 >= n) return;
  int base = ((const int*)(ws + OFF_AOFF))[c];
  const int* lst = (const int*)(ws + OFF_LIST) + c*BB;
  const float* E = ws + OFF_AN + (size_t)base;
  const float* fpos = ws + OFF_F + c*BB;
  const float* dpos = ws + OFF_DINV + c*BB;
  const float* srcc = src + (size_t)c*(size_t)chanStride*64;
  __shared__ float cf[16][128];
  __shared__ float sl[128][64];
  __shared__ float frow_s[16];
  int wv = threadIdx.x >> 6, lane = threadIdx.x & 63;
  if (threadIdx.x < 16){
    int rr = r0 + threadIdx.x;
    frow_s[threadIdx.x] = (rr < n) ? fpos[rr] : 0.f;
  }
  int rw = wv*4;
  float acc[4] = {0.f,0.f,0.f,0.f};
  for (int jt = 0; jt < n; jt += 128){
    __syncthreads();
    #pragma unroll
    for (int s = 0; s < 8; s++){
      int slot = threadIdx.x + s*256;
      int j = slot >> 4, q = slot & 15;
      int jj = jt + j;
      float4 v = make_float4(0.f,0.f,0.f,0.f);
      if (jj < n){
        int jg = lst[jj];
        v = *(const float4*)&srcc[(size_t)jg*64 + q*4];
      }
      *(float4*)&sl[j][q*4] = v;
    }
    #pragma unroll
    for (int s = 0; s < 8; s++){
      int idx = threadIdx.x + s*256;
      int r = idx >> 7, j = idx & 127;
      int row = r0 + r, jj = jt + j;
      float v = 0.f;
      if (row < n && jj < n){
        if (jj == row){ float d = dpos[row]; v = d*d; }
        else v = E[(size_t)row*n + jj] * fpos[jj] * frow_s[r];
      }
      cf[r][j] = v;
    }
    __syncthreads();
    int jcnt = n - jt; if (jcnt > 128) jcnt = 128;
    int jcnt4 = (jcnt + 3) & ~3;
    for (int j = 0; j < jcnt4; j += 4){
      float v0 = sl[j+0][lane];
      float v1 = sl[j+1][lane];
      float v2 = sl[j+2][lane];
      float v3 = sl[j+3][lane];
      #pragma unroll
      for (int r = 0; r < 4; r++){
        float4 c4 = *(const float4*)&cf[rw + r][j];
        acc[r] += c4.x*v0 + c4.y*v1 + c4.z*v2 + c4.w*v3;
      }
    }
  }
  float bl = bias[lane];
  float s = 0.f, ssq = 0.f;
  #pragma unroll
  for (int r = 0; r < 4; r++){
    int row = r0 + rw + r;
    if (row < n){
      float a = fmaxf(acc[r] + bl, 0.f);
      outb[((size_t)c*BB + lst[row])*64 + lane] = a;
      s += a; ssq += a*a;
    }
  }
  s = wsum64(s); ssq = wsum64(ssq);
  __shared__ float shs[4], shq[4];
  if (lane == 0){ shs[wv] = s; shq[wv] = ssq; }
  __syncthreads();
  if (threadIdx.x == 0){
    float ts = shs[0]+shs[1]+shs[2]+shs[3];
    float tq = shq[0]+shq[1]+shq[2]+shq[3];
    if (tq != 0.f){
      atomicAdd(statsb + 2*c,     ts);
      atomicAdd(statsb + 2*c + 1, tq);
    }
  }
}

// ---- K12: x1n = masked_ln(x1); y = x1n @ gcn2_w (in place over x1) ---------
__global__ __launch_bounds__(256) void k_y(const float* __restrict__ w2g, float* __restrict__ ws){
  __shared__ float w2s[64][65];
  __shared__ float xs[4][64];
  int wv = threadIdx.x >> 6, lane = threadIdx.x & 63;
  for (int q = threadIdx.x; q < 4096; q += 256) w2s[q >> 6][q & 63] = w2g[q];
  __syncthreads();
  int c = blockIdx.x;
  int n = ((const int*)(ws + OFF_CNT))[c];
  const int* list = (const int*)(ws + OFF_LIST);
  float* x1 = ws + OFF_X1;
  float cntf = fmaxf((float)(n*64), 1.f);
  float mu = ws[OFF_X1S + 2*c]/cntf;
  float var = ws[OFF_X1S + 2*c + 1]/cntf - mu*mu;
  float rs = rsqrtf(var + 1e-5f);
  for (int ii = blockIdx.y*4 + wv; ii < n; ii += 64){   // gridDim.y = 16
    int i = list[c*BB + ii];
    size_t bse = ((size_t)c*BB + i)*64;
    float xn = (x1[bse + lane] - mu)*rs;
    xs[wv][lane] = xn;
    float y0 = 0.f, y1 = 0.f, y2 = 0.f, y3 = 0.f;
    #pragma unroll
    for (int k = 0; k < 64; k += 4){
      float4 xq = *(const float4*)&xs[wv][k];
      y0 += xq.x*w2s[k][lane];
      y1 += xq.y*w2s[k+1][lane];
      y2 += xq.z*w2s[k+2][lane];
      y3 += xq.w*w2s[k+3][lane];
    }
    x1[bse + lane] = (y0+y1) + (y2+y3);
  }
}

// ---- K13: final head (R9-proven: 256 blocks, 1 row/wave, inline x2-norm) ---
__global__ __launch_bounds__(256) void k_final(const float* __restrict__ pw1,
                                               const float* __restrict__ pb1,
                                               const float* __restrict__ pg,
                                               const float* __restrict__ pbe,
                                               const float* __restrict__ pw2,
                                               const float* __restrict__ pb2,
                                               float* __restrict__ ws,
                                               float* __restrict__ out){
  __shared__ float fr[4][FULLW];
  int wv = threadIdx.x >> 6, lane = threadIdx.x & 63;
  int b = blockIdx.x*4 + wv;
  const int* cols = (const int*)(ws + OFF_COLS);
  const int* cnt  = (const int*)(ws + OFF_CNT);
  const float* x2 = ws + OFF_X2;
  const float* fe3 = ws + OFF_FE3;
  #pragma unroll
  for (int t = 0; t < KK; t++){
    int ct = cols[b*KK + t];
    float cfv = fmaxf((float)(cnt[ct]*64), 1.f);
    float mu = ws[OFF_X2S + 2*ct]/cfv;
    float var = ws[OFF_X2S + 2*ct + 1]/cfv - mu*mu;
    float rs = rsqrtf(var + 1e-5f);
    fr[wv][t*64 + lane] = (x2[((size_t)ct*BB + b)*64 + lane] - mu)*rs;
  }
  #pragma unroll
  for (int q = 0; q < 32; q++) fr[wv][512 + q*64 + lane] = fe3[b*CH + q*64 + lane];
  __syncthreads();
  float a0 = 0.f, a1 = 0.f, a2 = 0.f, a3 = 0.f;
  #pragma unroll 8
  for (int k = 0; k < FULLW; k += 4){
    float4 fq = *(const float4*)&fr[wv][k];
    a0 += fq.x*pw1[(k+0)*64 + lane];
    a1 += fq.y*pw1[(k+1)*64 + lane];
    a2 += fq.z*pw1[(k+2)*64 + lane];
    a3 += fq.w*pw1[(k+3)*64 + lane];
  }
  float acc = (a0+a1) + (a2+a3) + pb1[lane];
  acc = fmaxf(acc, 0.f);
  float mu = wsum64(acc)*(1.f/64.f);
  float d = acc - mu;
  float var = wsum64(d*d)*(1.f/64.f);
  float rs = rsqrtf(var + 1e-5f);
  float zn = d*rs*pg[lane] + pbe[lane];
  float s0 = wsum64(zn*pw2[lane*2 + 0]);
  float s1 = wsum64(zn*pw2[lane*2 + 1]);
  if (lane == 0){
    out[b*2 + 0] = s0 + pb2[0];
    out[b*2 + 1] = s1 + pb2[1];
  }
}

extern "C" void kernel_launch(void* const* d_in, const int* in_sizes, int n_in,
                              void* d_out, int out_size, void* d_ws, size_t ws_size,
                              hipStream_t stream){
  (void)in_sizes; (void)n_in; (void)out_size; (void)ws_size;
  const float* num_data = (const float*)d_in[0];
  const int*   cat_data = (const int*)d_in[1];
  const float* num_w   = (const float*)d_in[2];
  const float* num_b   = (const float*)d_in[3];
  const float* cat_emb = (const float*)d_in[4];
  const float* fi_w1   = (const float*)d_in[5];
  const float* fi_b1   = (const float*)d_in[6];
  const float* fi_g    = (const float*)d_in[7];
  const float* fi_be   = (const float*)d_in[8];
  const float* fi_w2   = (const float*)d_in[9];
  const float* fi_b2   = (const float*)d_in[10];
  const float* gcn1_w  = (const float*)d_in[11];
  const float* gcn1_b  = (const float*)d_in[12];
  const float* gcn2_w  = (const float*)d_in[13];
  const float* gcn2_b  = (const float*)d_in[14];
  const float* pw1     = (const float*)d_in[15];
  const float* pb1     = (const float*)d_in[16];
  const float* pg      = (const float*)d_in[17];
  const float* pbe     = (const float*)d_in[18];
  const float* pw2     = (const float*)d_in[19];
  const float* pb2     = (const float*)d_in[20];
  float* ws  = (float*)d_ws;
  float* out = (float*)d_out;

  k_init<<<1, 256, 0, stream>>>(ws);
  k_fe<<<2048, 256, 0, stream>>>(num_data, num_w, num_b, cat_data, cat_emb, ws);
  k_fi<<<1024, 256, 0, stream>>>(fi_w1, fi_b1, fi_g, fi_be, fi_w2, fi_b2, ws);
  k_topk<<<1024, 256, 0, stream>>>(ws);
  k_lists<<<32, 256, 0, stream>>>(ws);
  k_offs<<<1, 64, 0, stream>>>(ws);
  k_G<<<256, 256, 0, stream>>>(gcn1_w, ws);
  k_E<<<dim3(32, 32), 256, 0, stream>>>(ws);
  k_scl<<<dim3(32, 4), 256, 0, stream>>>(ws);
  k_agg<<<dim3(32, 64), 256, 0, stream>>>(ws + OFF_G, 0, gcn1_b, ws + OFF_X1, ws + OFF_X1S, ws);
  k_y<<<dim3(32, 16), 256, 0, stream>>>(gcn2_w, ws);
  k_agg<<<dim3(32, 64), 256, 0, stream>>>(ws + OFF_X1, BB, gcn2_b, ws + OFF_X2, ws + OFF_X2S, ws);
  k_final<<<256, 256, 0, stream>>>(pw1, pb1, pg, pbe, pw2, pb2, ws, out);
}